// Round 9
// baseline (849.860 us; speedup 1.0000x reference)
//
#include <hip/hip_runtime.h>

// Stacked LSTM B=2048,T=512,IN=4,H=64,L=4,OUT=5 — R15 EXACT structure +
// split accumulators + partner fast-spin. RESUBMIT of R18 (infra failure,
// no verdict) with bounded-spin safety: partner poll spins 64 probes then
// s_sleep(1) (steady state unaffected; pathological convoys don't hammer
// LDS). Scoreboard: R10 603 / R11 639 / R12 713 / R13 965 / R14 540 /
// R15 509 CHAMPION / R16 552 / R17 570 / R18 no-result.
// R16/R17 lesson (2x confirmed): poll VALU executes inside wait windows —
// cutting it buys nothing; both edits lengthened dependency chains and
// regressed. The wall is LATENCY/HANDOFF-bound. This round shortens chains
// only:
//  1. SPLIT ACCUMULATORS: accA = kt2(C=bias) -> kt0; accB = kt3(C=0) ->
//     kt1. Phase-1 MFMAs independent, phase-2 MFMAs independent: serial
//     MFMA depth on the handoff path 4 -> 2, phase-2 depth 2 -> 1 (pointwise
//     starts one MFMA latency earlier). Cost: +8 VALU adds/lane-step (merge).
//  2. PARTNER POLL FAST-SPIN: no sleep for first 64 probes (s_sleep
//     quantizes wake latency to ~64-cyc granules on the per-step tight
//     edge); sleep thereafter; guard-break at 2^16 (degrade, don't hang).
// Ring protocol (R14/R15-proven, unchanged): 16 waves, depth-4 slot ring,
// identity-k layout rows 128 B XOR-swizzled ((r&7)<<4 both sides); input(t)
// of layer l read directly from layer l-1's own-h slot (t+1)&3; GEMM split
// kt2/kt3 after prev-poll, kt0/kt1 after partner-poll; setprio(1) around
// the critical section; 8-trans pointwise; scaled cell state C'=2log2e*c;
// bias in MFMA C-operand of accA.
// Flag deps before step t: partners >= t, prev >= t+1, next >= t-3 (WAR).
// A-frag: row=lane&15 (batch), k=(lane>>4)*8+e (unit, identity).
// C: col=lane&15 (unit), row=(lane>>4)*4+reg (rows 4q+rr, rr<2 real).

#define B_    2048
#define T_    512
#define H_    64
#define OUT_  5
#define LOG2E 1.44269504088896340736f

typedef _Float16 f16;
typedef __attribute__((ext_vector_type(4))) _Float16 f16x4;
typedef __attribute__((ext_vector_type(8))) _Float16 f16x8;
typedef __attribute__((ext_vector_type(4))) float f32x4;
typedef __attribute__((ext_vector_type(2))) unsigned long long u64x2;

__device__ __forceinline__ float rcpf(float v) { return __builtin_amdgcn_rcpf(v); }
__device__ __forceinline__ float ex2(float v)  { return __builtin_amdgcn_exp2f(v); }

__global__ __launch_bounds__(1024, 4) void lstm_ring6_k(
    const float* __restrict__ x,      // [B,T,4]
    const float* __restrict__ W_ih0,  // [256,4]
    const float* __restrict__ W_ihr,  // [3,256,64]
    const float* __restrict__ W_hh,   // [4,256,64]
    const float* __restrict__ b_ih,   // [4,256]
    const float* __restrict__ b_hh,   // [4,256]
    const float* __restrict__ W_fc,   // [5,64]
    const float* __restrict__ b_fc,   // [5]
    float* __restrict__ out)          // [B,5]
{
    const int tid  = threadIdx.x;
    const int wave = tid >> 6;        // 0..15
    const int l    = wave >> 2;       // layer 0..3
    const int jj   = wave & 3;        // quarter of the layer's units
    const int lane = tid & 63;
    const int q    = lane >> 4;
    const int ln   = lane & 15;
    const int b0   = blockIdx.x * 8;

    // [layer][slot 0..3][16 rows x 64 f16], row=128 B, XOR-swizzled. 32 KB.
    __shared__ f16  hbuf[4][4][1024];
    __shared__ f16  xlds[T_][8][4];    // 32 KB
    __shared__ float hf[8][H_ + 1];    // FC staging
    __shared__ int  flg[16];

    for (int k = tid; k < 8192; k += 1024) ((unsigned*)hbuf)[k] = 0u;
    if (tid < 16) flg[tid] = 0;

    // ---- one-time x preload -> xlds (f16), coalesced float4 reads ----
#pragma unroll
    for (int k = 0; k < 4; ++k) {
        const int idx = tid + k * 1024;              // 0..4095
        const int bb  = idx >> 9, tt = idx & 511;
        const float4 v = *(const float4*)(x + (size_t)(b0 + bb) * (T_ * 4) + tt * 4);
        f16x4 h4; h4[0] = (f16)v.x; h4[1] = (f16)v.y; h4[2] = (f16)v.z; h4[3] = (f16)v.w;
        *(f16x4*)&xlds[tt][bb][0] = h4;
    }

    // ---- weights -> f16 B-frags (4 gates x 4 kt = 64 VGPR), prescaled ----
    const float* Whh = W_hh + (size_t)l * 256 * 64;
    const float* Wih = (l == 0) ? W_ih0 : (W_ihr + (size_t)(l - 1) * 256 * 64);
    const float scg[4] = {-LOG2E, -LOG2E, 2.0f * LOG2E, -LOG2E};

    f16x8 Wf[4][4];                   // [gate][kt]; kt0/1 = h, kt2/3 = input
    f32x4 Cb[4];                      // bias as MFMA C-init (broadcast rows)
#pragma unroll
    for (int g4 = 0; g4 < 4; ++g4) {
        const int n = g4 * 64 + jj * 16 + ln;
        const float bv = (b_ih[l * 256 + n] + b_hh[l * 256 + n]) * scg[g4];
        Cb[g4][0] = bv; Cb[g4][1] = bv; Cb[g4][2] = bv; Cb[g4][3] = bv;
#pragma unroll
        for (int kt = 0; kt < 4; ++kt) {
            f16x8 f;
#pragma unroll
            for (int e = 0; e < 8; ++e) {
                float wv;
                if (kt < 2)      wv = Whh[n * 64 + kt * 32 + q * 8 + e];
                else if (l == 0) wv = (kt == 2 && q == 0 && e < 4) ? Wih[n * 4 + e] : 0.0f;
                else             wv = Wih[n * 64 + (kt - 2) * 32 + q * 8 + e];
                f[e] = (f16)(wv * scg[g4]);
            }
            Wf[g4][kt] = f;
        }
    }

    // ---- per-lane LDS byte offsets (swizzled) ----
    const int swz   = (ln & 7) << 4;
    const int roffA = (ln * 128 + q * 16) ^ swz;        // k-octets 0..3
    const int roffB = (ln * 128 + 64 + q * 16) ^ swz;   // k-octets 4..7
    char* ownB      = (char*)&hbuf[l][0][0];
    const char* prvB = (const char*)&hbuf[(l > 0) ? (l - 1) : 0][0][0];

    int woff[2];
#pragma unroll
    for (int rr = 0; rr < 2; ++rr) {
        const int r = 4 * q + rr;
        woff[rr] = (r * 128 + (jj * 16 + ln) * 2) ^ ((r & 7) << 4);
    }
    const int  xb  = 2 * (ln >> 2) + (ln & 1);      // batch for x-frag row ln
    const bool xok = (q == 0) && ((ln & 3) < 2);    // real batch rows only

    // ---- flag-watch lane assignments (R15 split polls) ----
    const bool fU1 = (l > 0) && (lane < 4);         // prev >= t+1
    const int  fI1 = fU1 ? (4 * (l - 1) + lane) : 0;
    int fI2 = 0, fO2 = 0; bool fU2 = false;         // partners >= t; next >= t-3
    if (lane < 3)                { fI2 = 4 * l + ((jj + 1 + lane) & 3); fO2 = 0;  fU2 = true; }
    else if (lane < 7 && l < 3)  { fI2 = 4 * (l + 1) + (lane - 3);      fO2 = -3; fU2 = true; }

    __syncthreads();                  // zero-init + xlds + flg visible

    const f32x4 Z0 = {0.f, 0.f, 0.f, 0.f};
    float cst[2] = {0.f, 0.f};        // SCALED cell state C' = 2log2e * c
    const float K2 = 2.0f * LOG2E;

    auto body = [&](const int t, const int sl, const int sn) {
        // ---- phase 1: input half (off the recurrence) ----
        // accA = kt2 (C=bias); accB = kt3 (C=0) — INDEPENDENT chains.
        f32x4 accA[4], accB[4];
        if (l > 0) {
            unsigned g = 0;                          // poll prev >= t+1
            for (;;) {
                int v = 0x7fffffff;
                if (fU1) v = __hip_atomic_load(&flg[fI1], __ATOMIC_ACQUIRE,
                                               __HIP_MEMORY_SCOPE_WORKGROUP);
                if (__all(v >= t + 1)) break;
                if (++g > 2) __builtin_amdgcn_s_sleep(1);
                if (g > (1u << 16)) break;
            }
            const char* ri = prvB + sn * 2048;       // h_{l-1}(t)
            const f16x8 A2 = *(const f16x8*)(ri + roffA);
            const f16x8 A3 = *(const f16x8*)(ri + roffB);
#pragma unroll
            for (int g4 = 0; g4 < 4; ++g4)
                accA[g4] = __builtin_amdgcn_mfma_f32_16x16x32_f16(A2, Wf[g4][2], Cb[g4], 0, 0, 0);
#pragma unroll
            for (int g4 = 0; g4 < 4; ++g4)
                accB[g4] = __builtin_amdgcn_mfma_f32_16x16x32_f16(A3, Wf[g4][3], Z0, 0, 0, 0);
        } else {
            unsigned long long xw = 0ull;
            if (xok) xw = *(const unsigned long long*)&xlds[t][xb][0];
            u64x2 tmp; tmp[0] = xw; tmp[1] = 0ull;
            const f16x8 A2 = __builtin_bit_cast(f16x8, tmp);  // x(t) @ k=64..67
#pragma unroll
            for (int g4 = 0; g4 < 4; ++g4)
                accA[g4] = __builtin_amdgcn_mfma_f32_16x16x32_f16(A2, Wf[g4][2], Cb[g4], 0, 0, 0);
#pragma unroll
            for (int g4 = 0; g4 < 4; ++g4)
                accB[g4] = Z0;                       // kt3 identically 0 for l==0
        }

        // ---- phase 2: recurrence-critical half ----
        {
            unsigned g = 0;                          // partners >= t, next >= t-3
            for (;;) {                               // fast-spin 64, then sleep
                int v = 0x7fffffff;
                if (fU2) v = __hip_atomic_load(&flg[fI2], __ATOMIC_ACQUIRE,
                                               __HIP_MEMORY_SCOPE_WORKGROUP);
                if (__all(v >= t + fO2)) break;
                if (++g > 64) __builtin_amdgcn_s_sleep(1);
                if (g > (1u << 16)) break;           // degrade, don't hang
            }
        }
        const char* ro = ownB + sl * 2048;           // h_l(t-1)
        const f16x8 A0 = *(const f16x8*)(ro + roffA);
        const f16x8 A1 = *(const f16x8*)(ro + roffB);
        __builtin_amdgcn_s_setprio(1);
#pragma unroll
        for (int g4 = 0; g4 < 4; ++g4)
            accA[g4] = __builtin_amdgcn_mfma_f32_16x16x32_f16(A0, Wf[g4][0], accA[g4], 0, 0, 0);
#pragma unroll
        for (int g4 = 0; g4 < 4; ++g4)
            accB[g4] = __builtin_amdgcn_mfma_f32_16x16x32_f16(A1, Wf[g4][1], accB[g4], 0, 0, 0);

        // ---- pointwise: 8 trans/update, accA+accB merged here ----
        char* wr = ownB + sn * 2048;                 // h(t) -> slot (t+1)&3
#pragma unroll
        for (int rr = 0; rr < 2; ++rr) {
            const float gi = accA[0][rr] + accB[0][rr];
            const float gf = accA[1][rr] + accB[1][rr];
            const float gg = accA[2][rr] + accB[2][rr];
            const float go = accA[3][rr] + accB[3][rr];
            const float Ei = ex2(gi);                // e^{-i}
            const float Ef = ex2(gf);                // e^{-f}
            const float Eg = ex2(gg);                // e^{+2g}
            const float Eo = ex2(go);                // e^{-o}
            const float sf   = rcpf(1.0f + Ef);                  // sigmoid(f)
            const float di   = (1.0f + Ei) * (1.0f + Eg);
            const float sitg = fmaf(Eg, K2, -K2) * rcpf(di);     // 2log2e*si*tg
            const float Cp   = fmaf(sf, cst[rr], sitg);          // C'=2log2e*c
            cst[rr] = Cp;
            const float Ec = ex2(Cp);                // e^{+2c}
            const float dc = (1.0f + Eo) * (1.0f + Ec);
            const float h  = (Ec - 1.0f) * rcpf(dc); // sigmoid(o)*tanh(c)
            *(f16*)(wr + woff[rr]) = (f16)h;
            if (l == 3 && t == T_ - 1) hf[2 * q + rr][jj * 16 + ln] = h;
        }
        __builtin_amdgcn_s_setprio(0);

        if (lane == 0)                // release: drains LDS writes first
            __hip_atomic_store(&flg[wave], t + 1, __ATOMIC_RELEASE,
                               __HIP_MEMORY_SCOPE_WORKGROUP);
    };

#pragma unroll 1
    for (int t = 0; t < T_; t += 4) {                // slots folded to constants
        body(t,     0, 1);
        body(t + 1, 1, 2);
        body(t + 2, 2, 3);
        body(t + 3, 3, 0);
    }

    // ---- FC on h(T-1) of layer 3 ----
    __syncthreads();
    if (tid < 8 * OUT_) {
        const int b = tid / OUT_, o = tid % OUT_;
        float a = b_fc[o];
#pragma unroll
        for (int k = 0; k < H_; ++k)
            a = fmaf(hf[b][k], W_fc[o * H_ + k], a);
        out[(b0 + b) * OUT_ + o] = a;
    }
}

extern "C" void kernel_launch(void* const* d_in, const int* in_sizes, int n_in,
                              void* d_out, int out_size, void* d_ws, size_t ws_size,
                              hipStream_t stream) {
    const float* x     = (const float*)d_in[0];
    const float* W_ih0 = (const float*)d_in[1];
    const float* W_ihr = (const float*)d_in[2];
    const float* W_hh  = (const float*)d_in[3];
    const float* b_ih  = (const float*)d_in[4];
    const float* b_hh  = (const float*)d_in[5];
    const float* W_fc  = (const float*)d_in[6];
    const float* b_fc  = (const float*)d_in[7];
    float* out = (float*)d_out;

    lstm_ring6_k<<<dim3(B_ / 8), dim3(1024), 0, stream>>>(
        x, W_ih0, W_ihr, W_hh, b_ih, b_hh, W_fc, b_fc, out);
}

// Round 10
// 566.398 us; speedup vs baseline: 1.5005x; 1.5005x over previous
//
#include <hip/hip_runtime.h>

// Stacked LSTM B=2048,T=512,IN=4,H=64,L=4,OUT=5 — R15 champion, ONE edit:
// setprio window narrowed to the phase-2 MFMAs only (drop to prio 0 BEFORE
// the trans-heavy pointwise). Scoreboard: R10 603 / R11 639 / R12 713 /
// R13 965 / R14 540 / R15 509 CHAMPION / R16 552 / R17 570 / R19 850
// (busy-spin hammered LDS: sleeping waves donate issue+LDS bandwidth).
// Diagnosis this round: R15 shows MfmaUtil 44.5 + VALUBusy 63.6 = 108% —
// pipes ADDITIVE, ~870 cyc/step neither-pipe. T5 says prio belongs around
// the MFMA cluster ONLY; R14 grafted it around MFMA+pointwise. A wave
// grinding dependent trans at prio 1 starves prio-0 waves with READY MFMAs
// -> serialization -> additivity. This kernel A/Bs exactly that: setprio(0)
// moves from after-pointwise to after-kt1-MFMAs. Everything else is
// byte-identical to R15 (lstm_ring3_k):
// Ring: 16 waves, depth-4 slot ring, identity-k layout rows 128 B
// XOR-swizzled ((r&7)<<4 both sides); input(t) of layer l read directly
// from layer l-1's own-h slot (t+1)&3; GEMM split kt2(C=bias),kt3 after
// prev-poll / kt0,kt1 after partner-poll; polls sleep after 2 probes;
// 8-trans fused pointwise; scaled cell state C'=2log2e*c.
// Flag deps before step t: partners >= t, prev >= t+1, next >= t-3 (WAR).
// A-frag: row=lane&15 (batch), k=(lane>>4)*8+e (unit, identity).
// C: col=lane&15 (unit), row=(lane>>4)*4+reg (rows 4q+rr, rr<2 real).

#define B_    2048
#define T_    512
#define H_    64
#define OUT_  5
#define LOG2E 1.44269504088896340736f

typedef _Float16 f16;
typedef __attribute__((ext_vector_type(4))) _Float16 f16x4;
typedef __attribute__((ext_vector_type(8))) _Float16 f16x8;
typedef __attribute__((ext_vector_type(4))) float f32x4;
typedef __attribute__((ext_vector_type(2))) unsigned long long u64x2;

__device__ __forceinline__ float rcpf(float v) { return __builtin_amdgcn_rcpf(v); }
__device__ __forceinline__ float ex2(float v)  { return __builtin_amdgcn_exp2f(v); }

__global__ __launch_bounds__(1024, 4) void lstm_ring7_k(
    const float* __restrict__ x,      // [B,T,4]
    const float* __restrict__ W_ih0,  // [256,4]
    const float* __restrict__ W_ihr,  // [3,256,64]
    const float* __restrict__ W_hh,   // [4,256,64]
    const float* __restrict__ b_ih,   // [4,256]
    const float* __restrict__ b_hh,   // [4,256]
    const float* __restrict__ W_fc,   // [5,64]
    const float* __restrict__ b_fc,   // [5]
    float* __restrict__ out)          // [B,5]
{
    const int tid  = threadIdx.x;
    const int wave = tid >> 6;        // 0..15
    const int l    = wave >> 2;       // layer 0..3
    const int jj   = wave & 3;        // quarter of the layer's units
    const int lane = tid & 63;
    const int q    = lane >> 4;
    const int ln   = lane & 15;
    const int b0   = blockIdx.x * 8;

    // [layer][slot 0..3][16 rows x 64 f16], row=128 B, XOR-swizzled. 32 KB.
    __shared__ f16  hbuf[4][4][1024];
    __shared__ f16  xlds[T_][8][4];    // 32 KB
    __shared__ float hf[8][H_ + 1];    // FC staging
    __shared__ int  flg[16];

    for (int k = tid; k < 8192; k += 1024) ((unsigned*)hbuf)[k] = 0u;
    if (tid < 16) flg[tid] = 0;

    // ---- one-time x preload -> xlds (f16), coalesced float4 reads ----
#pragma unroll
    for (int k = 0; k < 4; ++k) {
        const int idx = tid + k * 1024;              // 0..4095
        const int bb  = idx >> 9, tt = idx & 511;
        const float4 v = *(const float4*)(x + (size_t)(b0 + bb) * (T_ * 4) + tt * 4);
        f16x4 h4; h4[0] = (f16)v.x; h4[1] = (f16)v.y; h4[2] = (f16)v.z; h4[3] = (f16)v.w;
        *(f16x4*)&xlds[tt][bb][0] = h4;
    }

    // ---- weights -> f16 B-frags (4 gates x 4 kt = 64 VGPR), prescaled ----
    const float* Whh = W_hh + (size_t)l * 256 * 64;
    const float* Wih = (l == 0) ? W_ih0 : (W_ihr + (size_t)(l - 1) * 256 * 64);
    const float scg[4] = {-LOG2E, -LOG2E, 2.0f * LOG2E, -LOG2E};

    f16x8 Wf[4][4];                   // [gate][kt]; kt0/1 = h, kt2/3 = input
    f32x4 Cb[4];                      // bias as MFMA C-init (broadcast rows)
#pragma unroll
    for (int g4 = 0; g4 < 4; ++g4) {
        const int n = g4 * 64 + jj * 16 + ln;
        const float bv = (b_ih[l * 256 + n] + b_hh[l * 256 + n]) * scg[g4];
        Cb[g4][0] = bv; Cb[g4][1] = bv; Cb[g4][2] = bv; Cb[g4][3] = bv;
#pragma unroll
        for (int kt = 0; kt < 4; ++kt) {
            f16x8 f;
#pragma unroll
            for (int e = 0; e < 8; ++e) {
                float wv;
                if (kt < 2)      wv = Whh[n * 64 + kt * 32 + q * 8 + e];
                else if (l == 0) wv = (kt == 2 && q == 0 && e < 4) ? Wih[n * 4 + e] : 0.0f;
                else             wv = Wih[n * 64 + (kt - 2) * 32 + q * 8 + e];
                f[e] = (f16)(wv * scg[g4]);
            }
            Wf[g4][kt] = f;
        }
    }

    // ---- per-lane LDS byte offsets (swizzled) ----
    const int swz   = (ln & 7) << 4;
    const int roffA = (ln * 128 + q * 16) ^ swz;        // k-octets 0..3
    const int roffB = (ln * 128 + 64 + q * 16) ^ swz;   // k-octets 4..7
    char* ownB      = (char*)&hbuf[l][0][0];
    const char* prvB = (const char*)&hbuf[(l > 0) ? (l - 1) : 0][0][0];

    int woff[2];
#pragma unroll
    for (int rr = 0; rr < 2; ++rr) {
        const int r = 4 * q + rr;
        woff[rr] = (r * 128 + (jj * 16 + ln) * 2) ^ ((r & 7) << 4);
    }
    const int  xb  = 2 * (ln >> 2) + (ln & 1);      // batch for x-frag row ln
    const bool xok = (q == 0) && ((ln & 3) < 2);    // real batch rows only

    // ---- flag-watch lane assignments (R15 split polls) ----
    const bool fU1 = (l > 0) && (lane < 4);         // prev >= t+1
    const int  fI1 = fU1 ? (4 * (l - 1) + lane) : 0;
    int fI2 = 0, fO2 = 0; bool fU2 = false;         // partners >= t; next >= t-3
    if (lane < 3)                { fI2 = 4 * l + ((jj + 1 + lane) & 3); fO2 = 0;  fU2 = true; }
    else if (lane < 7 && l < 3)  { fI2 = 4 * (l + 1) + (lane - 3);      fO2 = -3; fU2 = true; }

    __syncthreads();                  // zero-init + xlds + flg visible

    float cst[2] = {0.f, 0.f};        // SCALED cell state C' = 2log2e * c
    const float K2 = 2.0f * LOG2E;

    auto body = [&](const int t, const int sl, const int sn) {
        // ---- phase 1: input half (off the recurrence), C = bias ----
        f32x4 acc[4];
        if (l > 0) {
            unsigned g = 0;                          // poll prev >= t+1
            for (;;) {
                int v = 0x7fffffff;
                if (fU1) v = __hip_atomic_load(&flg[fI1], __ATOMIC_ACQUIRE,
                                               __HIP_MEMORY_SCOPE_WORKGROUP);
                if (__all(v >= t + 1)) break;
                if (++g > 2) __builtin_amdgcn_s_sleep(1);
                if (g > (1u << 16)) break;
            }
            const char* ri = prvB + sn * 2048;       // h_{l-1}(t)
            const f16x8 A2 = *(const f16x8*)(ri + roffA);
            const f16x8 A3 = *(const f16x8*)(ri + roffB);
#pragma unroll
            for (int g4 = 0; g4 < 4; ++g4)
                acc[g4] = __builtin_amdgcn_mfma_f32_16x16x32_f16(A2, Wf[g4][2], Cb[g4], 0, 0, 0);
#pragma unroll
            for (int g4 = 0; g4 < 4; ++g4)
                acc[g4] = __builtin_amdgcn_mfma_f32_16x16x32_f16(A3, Wf[g4][3], acc[g4], 0, 0, 0);
        } else {
            unsigned long long xw = 0ull;
            if (xok) xw = *(const unsigned long long*)&xlds[t][xb][0];
            u64x2 tmp; tmp[0] = xw; tmp[1] = 0ull;
            const f16x8 A2 = __builtin_bit_cast(f16x8, tmp);  // x(t) @ k=64..67
#pragma unroll
            for (int g4 = 0; g4 < 4; ++g4)
                acc[g4] = __builtin_amdgcn_mfma_f32_16x16x32_f16(A2, Wf[g4][2], Cb[g4], 0, 0, 0);
            // kt3 identically 0 for l==0: skipped (exact)
        }

        // ---- phase 2: recurrence-critical half ----
        {
            unsigned g = 0;                          // partners >= t, next >= t-3
            for (;;) {
                int v = 0x7fffffff;
                if (fU2) v = __hip_atomic_load(&flg[fI2], __ATOMIC_ACQUIRE,
                                               __HIP_MEMORY_SCOPE_WORKGROUP);
                if (__all(v >= t + fO2)) break;
                if (++g > 2) __builtin_amdgcn_s_sleep(1);
                if (g > (1u << 16)) break;
            }
        }
        const char* ro = ownB + sl * 2048;           // h_l(t-1)
        const f16x8 A0 = *(const f16x8*)(ro + roffA);
        const f16x8 A1 = *(const f16x8*)(ro + roffB);
        __builtin_amdgcn_s_setprio(1);               // prio: MFMA cluster ONLY
#pragma unroll
        for (int g4 = 0; g4 < 4; ++g4)
            acc[g4] = __builtin_amdgcn_mfma_f32_16x16x32_f16(A0, Wf[g4][0], acc[g4], 0, 0, 0);
#pragma unroll
        for (int g4 = 0; g4 < 4; ++g4)
            acc[g4] = __builtin_amdgcn_mfma_f32_16x16x32_f16(A1, Wf[g4][1], acc[g4], 0, 0, 0);
        __builtin_amdgcn_s_setprio(0);               // drop BEFORE trans chain

        // ---- pointwise: 8 trans/update (fused), scaled cell state ----
        char* wr = ownB + sn * 2048;                 // h(t) -> slot (t+1)&3
#pragma unroll
        for (int rr = 0; rr < 2; ++rr) {
            const float Ei = ex2(acc[0][rr]);        // e^{-i}
            const float Ef = ex2(acc[1][rr]);        // e^{-f}
            const float Eg = ex2(acc[2][rr]);        // e^{+2g}
            const float Eo = ex2(acc[3][rr]);        // e^{-o}
            const float sf   = rcpf(1.0f + Ef);                  // sigmoid(f)
            const float di   = (1.0f + Ei) * (1.0f + Eg);
            const float sitg = fmaf(Eg, K2, -K2) * rcpf(di);     // 2log2e*si*tg
            const float Cp   = fmaf(sf, cst[rr], sitg);          // C'=2log2e*c
            cst[rr] = Cp;
            const float Ec = ex2(Cp);                // e^{+2c}
            const float dc = (1.0f + Eo) * (1.0f + Ec);
            const float h  = (Ec - 1.0f) * rcpf(dc); // sigmoid(o)*tanh(c)
            *(f16*)(wr + woff[rr]) = (f16)h;
            if (l == 3 && t == T_ - 1) hf[2 * q + rr][jj * 16 + ln] = h;
        }

        if (lane == 0)                // release: drains LDS writes first
            __hip_atomic_store(&flg[wave], t + 1, __ATOMIC_RELEASE,
                               __HIP_MEMORY_SCOPE_WORKGROUP);
    };

#pragma unroll 1
    for (int t = 0; t < T_; t += 4) {                // slots folded to constants
        body(t,     0, 1);
        body(t + 1, 1, 2);
        body(t + 2, 2, 3);
        body(t + 3, 3, 0);
    }

    // ---- FC on h(T-1) of layer 3 ----
    __syncthreads();
    if (tid < 8 * OUT_) {
        const int b = tid / OUT_, o = tid % OUT_;
        float a = b_fc[o];
#pragma unroll
        for (int k = 0; k < H_; ++k)
            a = fmaf(hf[b][k], W_fc[o * H_ + k], a);
        out[(b0 + b) * OUT_ + o] = a;
    }
}

extern "C" void kernel_launch(void* const* d_in, const int* in_sizes, int n_in,
                              void* d_out, int out_size, void* d_ws, size_t ws_size,
                              hipStream_t stream) {
    const float* x     = (const float*)d_in[0];
    const float* W_ih0 = (const float*)d_in[1];
    const float* W_ihr = (const float*)d_in[2];
    const float* W_hh  = (const float*)d_in[3];
    const float* b_ih  = (const float*)d_in[4];
    const float* b_hh  = (const float*)d_in[5];
    const float* W_fc  = (const float*)d_in[6];
    const float* b_fc  = (const float*)d_in[7];
    float* out = (float*)d_out;

    lstm_ring7_k<<<dim3(B_ / 8), dim3(1024), 0, stream>>>(
        x, W_ih0, W_ihr, W_hh, b_ih, b_hh, W_fc, b_fc, out);
}

// Round 12
// 498.713 us; speedup vs baseline: 1.7041x; 1.1357x over previous
//
#include <hip/hip_runtime.h>

// Stacked LSTM B=2048,T=512,IN=4,H=64,L=4,OUT=5 — R15 ring + DOUBLE-TIME
// INPUT GEMM, odd-step row-permutation FIXED. Scoreboard: R10 603 / R14 540
// / R15 509 CHAMPION / R16 552 / R17 570 / R19 850 / R20 566 / R21 FAIL
// (absmax 2.8e-2: odd h-MFMA added Whh*h(t) to C regs 0,1 — h(t) lives at
// A-rows 0,1 mod 4 — while the t+1 gates in regs 2,3 got the ZERO rows).
// FIX: odd-step own-h A-read uses row ln^2. For A-row r≡2,3 (mod 4) that
// sources h(t)[b(r)] from stored row r&~2 (since rho(b(r))=r&~2=r^2), so
// the recurrence accumulates into regs 2,3; rows r≡0,1 source the
// never-written zero rows -> dead regs 0,1 untouched. Exact.
// Double-time scheme (R21): even step t computes input-half for t AND t+1
// in the padded M rows (row r: batch b=2*(r>>2)+(r&1), time t+((r>>1)&1)),
// C=bias; h-half(t) adds recurrence to regs 0,1 (rows 2,3 mod 4 of own-h
// are zero -> regs 2,3 ride through); odd step h-half only (this fix) +
// pointwise on regs 2,3. Per-wave MFMA 16 even / 8 odd (-25%); one
// prev-poll (>= t+2) + one input lgkm window per 2 steps. Ring safety
// re-proved in R21 (WAR: next>=t-3 still covers; prev overwrite of read
// slots gated by our release t+2 which follows our reads).
// Everything else byte-identical to R15: identity-k layout rows 128 B
// XOR-swizzled ((r&7)<<4 both sides); partner poll >= t before h-half;
// setprio(1) over h-MFMA+pointwise (R20: do NOT narrow); 8-trans fused
// pointwise; scaled cell C'=2log2e*c; polls sleep after 2 probes.
// A-frag: row=lane&15, k=(lane>>4)*8+e. C: col=lane&15 (unit),
// row=(lane>>4)*4+reg; lane q owns batches 2q,2q+1 at BOTH parities.

#define B_    2048
#define T_    512
#define H_    64
#define OUT_  5
#define LOG2E 1.44269504088896340736f

typedef _Float16 f16;
typedef __attribute__((ext_vector_type(4))) _Float16 f16x4;
typedef __attribute__((ext_vector_type(8))) _Float16 f16x8;
typedef __attribute__((ext_vector_type(4))) float f32x4;
typedef __attribute__((ext_vector_type(2))) unsigned long long u64x2;

__device__ __forceinline__ float rcpf(float v) { return __builtin_amdgcn_rcpf(v); }
__device__ __forceinline__ float ex2(float v)  { return __builtin_amdgcn_exp2f(v); }

__global__ __launch_bounds__(1024, 4) void lstm_ring9_k(
    const float* __restrict__ x,      // [B,T,4]
    const float* __restrict__ W_ih0,  // [256,4]
    const float* __restrict__ W_ihr,  // [3,256,64]
    const float* __restrict__ W_hh,   // [4,256,64]
    const float* __restrict__ b_ih,   // [4,256]
    const float* __restrict__ b_hh,   // [4,256]
    const float* __restrict__ W_fc,   // [5,64]
    const float* __restrict__ b_fc,   // [5]
    float* __restrict__ out)          // [B,5]
{
    const int tid  = threadIdx.x;
    const int wave = tid >> 6;        // 0..15
    const int l    = wave >> 2;       // layer 0..3
    const int jj   = wave & 3;        // quarter of the layer's units
    const int lane = tid & 63;
    const int q    = lane >> 4;
    const int ln   = lane & 15;
    const int b0   = blockIdx.x * 8;

    // [layer][slot 0..3][16 rows x 64 f16], row=128 B, XOR-swizzled. 32 KB.
    // Rows 2,3,6,7,10,11,14,15 stay ZERO forever (load-bearing).
    __shared__ f16  hbuf[4][4][1024];
    __shared__ f16  xlds[T_][8][4];    // 32 KB
    __shared__ float hf[8][H_ + 1];    // FC staging
    __shared__ int  flg[16];

    for (int k = tid; k < 8192; k += 1024) ((unsigned*)hbuf)[k] = 0u;
    if (tid < 16) flg[tid] = 0;

    // ---- one-time x preload -> xlds (f16), coalesced float4 reads ----
#pragma unroll
    for (int k = 0; k < 4; ++k) {
        const int idx = tid + k * 1024;              // 0..4095
        const int bb  = idx >> 9, tt = idx & 511;
        const float4 v = *(const float4*)(x + (size_t)(b0 + bb) * (T_ * 4) + tt * 4);
        f16x4 h4; h4[0] = (f16)v.x; h4[1] = (f16)v.y; h4[2] = (f16)v.z; h4[3] = (f16)v.w;
        *(f16x4*)&xlds[tt][bb][0] = h4;
    }

    // ---- weights -> f16 B-frags (4 gates x 4 kt = 64 VGPR), prescaled ----
    const float* Whh = W_hh + (size_t)l * 256 * 64;
    const float* Wih = (l == 0) ? W_ih0 : (W_ihr + (size_t)(l - 1) * 256 * 64);
    const float scg[4] = {-LOG2E, -LOG2E, 2.0f * LOG2E, -LOG2E};

    f16x8 Wf[4][4];                   // [gate][kt]; kt0/1 = h, kt2/3 = input
    f32x4 Cb[4];                      // bias C-init (all 4 rows: both times)
#pragma unroll
    for (int g4 = 0; g4 < 4; ++g4) {
        const int n = g4 * 64 + jj * 16 + ln;
        const float bv = (b_ih[l * 256 + n] + b_hh[l * 256 + n]) * scg[g4];
        Cb[g4][0] = bv; Cb[g4][1] = bv; Cb[g4][2] = bv; Cb[g4][3] = bv;
#pragma unroll
        for (int kt = 0; kt < 4; ++kt) {
            f16x8 f;
#pragma unroll
            for (int e = 0; e < 8; ++e) {
                float wv;
                if (kt < 2)      wv = Whh[n * 64 + kt * 32 + q * 8 + e];
                else if (l == 0) wv = (kt == 2 && q == 0 && e < 4) ? Wih[n * 4 + e] : 0.0f;
                else             wv = Wih[n * 64 + (kt - 2) * 32 + q * 8 + e];
                f[e] = (f16)(wv * scg[g4]);
            }
            Wf[g4][kt] = f;
        }
    }

    // ---- per-lane LDS byte offsets (swizzled) ----
    const int swz   = (ln & 7) << 4;
    const int roffA = (ln * 128 + q * 16) ^ swz;        // even h-read, k 0..3
    const int roffB = (ln * 128 + 64 + q * 16) ^ swz;   // even h-read, k 4..7
    const int lnx   = ln ^ 2;                           // ODD-step row perm (FIX)
    const int swzx  = (lnx & 7) << 4;
    const int roffAx = (lnx * 128 + q * 16) ^ swzx;
    const int roffBx = (lnx * 128 + 64 + q * 16) ^ swzx;
    // double-time input source: row = rho(batch), slot by time bit
    const int srcrow = 4 * (ln >> 2) + (ln & 1);        // rho(b(ln))
    const int swz2   = (srcrow & 7) << 4;
    const int roffA2 = (srcrow * 128 + q * 16) ^ swz2;
    const int roffB2 = (srcrow * 128 + 64 + q * 16) ^ swz2;
    const int tsel   = (ln >> 1) & 1;                   // row carries time t+tsel
    char* ownB      = (char*)&hbuf[l][0][0];
    const char* prvB = (const char*)&hbuf[(l > 0) ? (l - 1) : 0][0][0];

    int woff[2];
#pragma unroll
    for (int rr = 0; rr < 2; ++rr) {
        const int r = 4 * q + rr;
        woff[rr] = (r * 128 + (jj * 16 + ln) * 2) ^ ((r & 7) << 4);
    }
    const int  xb2 = 2 * (ln >> 2) + (ln & 1);      // batch for x double-time row
    const bool xok = (lane < 16);                   // q==0: all 16 rows real

    // ---- flag-watch lane assignments (R15 split polls) ----
    const bool fU1 = (l > 0) && (lane < 4);         // prev >= t+2 (even steps)
    const int  fI1 = fU1 ? (4 * (l - 1) + lane) : 0;
    int fI2 = 0, fO2 = 0; bool fU2 = false;         // partners >= t; next >= t-3
    if (lane < 3)                { fI2 = 4 * l + ((jj + 1 + lane) & 3); fO2 = 0;  fU2 = true; }
    else if (lane < 7 && l < 3)  { fI2 = 4 * (l + 1) + (lane - 3);      fO2 = -3; fU2 = true; }

    __syncthreads();                  // zero-init + xlds + flg visible

    float cst[2] = {0.f, 0.f};        // SCALED cell state C' = 2log2e * c
    const float K2 = 2.0f * LOG2E;

    // pointwise on regs ra, ra+1 -> h(t) to slot sn
    auto pointwise = [&](const int t, const int sn, f32x4 (&acc)[4], const int ra) {
        char* wr = ownB + sn * 2048;
#pragma unroll
        for (int rr = 0; rr < 2; ++rr) {
            const int rg = ra + rr;
            const float Ei = ex2(acc[0][rg]);
            const float Ef = ex2(acc[1][rg]);
            const float Eg = ex2(acc[2][rg]);
            const float Eo = ex2(acc[3][rg]);
            const float sf   = rcpf(1.0f + Ef);
            const float di   = (1.0f + Ei) * (1.0f + Eg);
            const float sitg = fmaf(Eg, K2, -K2) * rcpf(di);
            const float Cp   = fmaf(sf, cst[rr], sitg);
            cst[rr] = Cp;
            const float Ec = ex2(Cp);
            const float dc = (1.0f + Eo) * (1.0f + Ec);
            const float h  = (Ec - 1.0f) * rcpf(dc);
            *(f16*)(wr + woff[rr]) = (f16)h;
            if (l == 3 && t == T_ - 1) hf[2 * q + rr][jj * 16 + ln] = h;
        }
    };

    auto partner_poll = [&](const int t) {
        unsigned g = 0;
        for (;;) {
            int v = 0x7fffffff;
            if (fU2) v = __hip_atomic_load(&flg[fI2], __ATOMIC_ACQUIRE,
                                           __HIP_MEMORY_SCOPE_WORKGROUP);
            if (__all(v >= t + fO2)) break;
            if (++g > 2) __builtin_amdgcn_s_sleep(1);
            if (g > (1u << 16)) break;
        }
    };

    auto release = [&](const int t) {
        if (lane == 0)
            __hip_atomic_store(&flg[wave], t + 1, __ATOMIC_RELEASE,
                               __HIP_MEMORY_SCOPE_WORKGROUP);
    };

    // EVEN step t: input-half for t AND t+1 (double-time M rows) + h-half(t).
    auto evenb = [&](const int t, const int sl, const int sn, const int sn2,
                     f32x4 (&acc)[4]) {
        if (l > 0) {
            unsigned g = 0;                          // poll prev >= t+2
            for (;;) {
                int v = 0x7fffffff;
                if (fU1) v = __hip_atomic_load(&flg[fI1], __ATOMIC_ACQUIRE,
                                               __HIP_MEMORY_SCOPE_WORKGROUP);
                if (__all(v >= t + 2)) break;
                if (++g > 2) __builtin_amdgcn_s_sleep(1);
                if (g > (1u << 16)) break;
            }
            const char* ri = prvB + (tsel ? sn2 : sn) * 2048;  // h_{l-1}(t+tsel)
            const f16x8 A2 = *(const f16x8*)(ri + roffA2);
            const f16x8 A3 = *(const f16x8*)(ri + roffB2);
#pragma unroll
            for (int g4 = 0; g4 < 4; ++g4)
                acc[g4] = __builtin_amdgcn_mfma_f32_16x16x32_f16(A2, Wf[g4][2], Cb[g4], 0, 0, 0);
#pragma unroll
            for (int g4 = 0; g4 < 4; ++g4)
                acc[g4] = __builtin_amdgcn_mfma_f32_16x16x32_f16(A3, Wf[g4][3], acc[g4], 0, 0, 0);
        } else {
            unsigned long long xw = 0ull;
            if (xok) xw = *(const unsigned long long*)&xlds[t + tsel][xb2][0];
            u64x2 tmp; tmp[0] = xw; tmp[1] = 0ull;
            const f16x8 A2 = __builtin_bit_cast(f16x8, tmp);  // x(t+tsel) @ k=64..67
#pragma unroll
            for (int g4 = 0; g4 < 4; ++g4)
                acc[g4] = __builtin_amdgcn_mfma_f32_16x16x32_f16(A2, Wf[g4][2], Cb[g4], 0, 0, 0);
            // kt3 identically 0 for l==0: skipped (exact)
        }

        partner_poll(t);
        const char* ro = ownB + sl * 2048;           // h_l(t-1), rows = ln
        const f16x8 A0 = *(const f16x8*)(ro + roffA);
        const f16x8 A1 = *(const f16x8*)(ro + roffB);
        __builtin_amdgcn_s_setprio(1);               // R15 window: MFMA+pointwise
#pragma unroll
        for (int g4 = 0; g4 < 4; ++g4)
            acc[g4] = __builtin_amdgcn_mfma_f32_16x16x32_f16(A0, Wf[g4][0], acc[g4], 0, 0, 0);
#pragma unroll
        for (int g4 = 0; g4 < 4; ++g4)
            acc[g4] = __builtin_amdgcn_mfma_f32_16x16x32_f16(A1, Wf[g4][1], acc[g4], 0, 0, 0);
        pointwise(t, sn, acc, 0);                    // regs 0,1 = step t
        __builtin_amdgcn_s_setprio(0);
        release(t);
    };

    // ODD step t: h-half with ROW PERM ln^2 (recurrence -> regs 2,3).
    auto oddb = [&](const int t, const int sl, const int sn, f32x4 (&acc)[4]) {
        partner_poll(t);
        const char* ro = ownB + sl * 2048;           // h_l(t-1), rows = ln^2
        const f16x8 A0 = *(const f16x8*)(ro + roffAx);
        const f16x8 A1 = *(const f16x8*)(ro + roffBx);
        __builtin_amdgcn_s_setprio(1);
#pragma unroll
        for (int g4 = 0; g4 < 4; ++g4)
            acc[g4] = __builtin_amdgcn_mfma_f32_16x16x32_f16(A0, Wf[g4][0], acc[g4], 0, 0, 0);
#pragma unroll
        for (int g4 = 0; g4 < 4; ++g4)
            acc[g4] = __builtin_amdgcn_mfma_f32_16x16x32_f16(A1, Wf[g4][1], acc[g4], 0, 0, 0);
        pointwise(t, sn, acc, 2);                    // regs 2,3 = step t
        __builtin_amdgcn_s_setprio(0);
        release(t);
    };

#pragma unroll 1
    for (int t = 0; t < T_; t += 4) {                // slots folded to constants
        f32x4 acc[4];
        evenb(t,     0, 1, 2, acc);
        oddb (t + 1, 1, 2,    acc);
        evenb(t + 2, 2, 3, 0, acc);
        oddb (t + 3, 3, 0,    acc);
    }

    // ---- FC on h(T-1) of layer 3 ----
    __syncthreads();
    if (tid < 8 * OUT_) {
        const int b = tid / OUT_, o = tid % OUT_;
        float a = b_fc[o];
#pragma unroll
        for (int k = 0; k < H_; ++k)
            a = fmaf(hf[b][k], W_fc[o * H_ + k], a);
        out[(b0 + b) * OUT_ + o] = a;
    }
}

extern "C" void kernel_launch(void* const* d_in, const int* in_sizes, int n_in,
                              void* d_out, int out_size, void* d_ws, size_t ws_size,
                              hipStream_t stream) {
    const float* x     = (const float*)d_in[0];
    const float* W_ih0 = (const float*)d_in[1];
    const float* W_ihr = (const float*)d_in[2];
    const float* W_hh  = (const float*)d_in[3];
    const float* b_ih  = (const float*)d_in[4];
    const float* b_hh  = (const float*)d_in[5];
    const float* W_fc  = (const float*)d_in[6];
    const float* b_fc  = (const float*)d_in[7];
    float* out = (float*)d_out;

    lstm_ring9_k<<<dim3(B_ / 8), dim3(1024), 0, stream>>>(
        x, W_ih0, W_ihr, W_hh, b_ih, b_hh, W_fc, b_fc, out);
}